// Round 1
// baseline (481.887 us; speedup 1.0000x reference)
//
#include <hip/hip_runtime.h>
#include <hip/hip_bf16.h>
#include <math.h>

#define S_LEN 2048
#define EDIM  1024
#define NHEAD 8
#define DHEAD 128
#define QT    32
#define JT    32
#define PAD   132   // 132%32==4 -> rows step-1 and step-4 hit distinct banks
#define NT    (S_LEN/QT)   // 64

// ---------------- Kernel 1: gate preactivations ----------------
// ig[h,s] = dot(concat(q,k,v)[s], igate_w[h]) + igate_b[h]; same for fg.
__global__ __launch_bounds__(256) void gates_kernel(
    const float* __restrict__ q, const float* __restrict__ k, const float* __restrict__ v,
    const float* __restrict__ iw, const float* __restrict__ ib,
    const float* __restrict__ fw, const float* __restrict__ fb,
    float* __restrict__ ig, float* __restrict__ fg)
{
  __shared__ float gi[3*EDIM];
  const int s = blockIdx.x;
  const int t = threadIdx.x;
  const float4* q4 = (const float4*)(q + (size_t)s*EDIM);
  const float4* k4 = (const float4*)(k + (size_t)s*EDIM);
  const float4* v4 = (const float4*)(v + (size_t)s*EDIM);
  float4* g4 = (float4*)gi;
  g4[t]       = q4[t];
  g4[t + 256] = k4[t];
  g4[t + 512] = v4[t];
  __syncthreads();
  const int w = t >> 6, lane = t & 63;
  for (int c = w; c < 16; c += 4) {
    const int h = c & 7;
    const int gate = c >> 3;
    const float* wr = (gate ? fw : iw) + (size_t)h*3*EDIM;
    float sum = 0.f;
    for (int e = lane; e < 3*EDIM; e += 64) sum += gi[e]*wr[e];
    #pragma unroll
    for (int off = 32; off; off >>= 1) sum += __shfl_xor(sum, off);
    if (lane == 0) {
      if (gate) fg[h*S_LEN + s] = sum + fb[h];
      else      ig[h*S_LEN + s] = sum + ib[h];
    }
  }
}

// ---------------- Kernel 2: per-head scans ----------------
// cs = cumsum(logsigmoid(fg)); a = ig - cs; M = prefixmax(a).
__global__ __launch_bounds__(256) void scan_kernel(
    const float* __restrict__ ig, const float* __restrict__ fg,
    float* __restrict__ cs, float* __restrict__ a, float* __restrict__ M)
{
  __shared__ float arr[256];
  const int h = blockIdx.x, t = threadIdx.x;
  const int base = t*8;
  const float* fgh = fg + h*S_LEN;
  const float* igh = ig + h*S_LEN;
  float lv[8];
  float loc = 0.f;
  #pragma unroll
  for (int i2 = 0; i2 < 8; ++i2) {
    float x = fgh[base + i2];
    float ls = fminf(x, 0.f) - log1pf(expf(-fabsf(x)));  // log_sigmoid
    lv[i2] = ls; loc += ls;
  }
  arr[t] = loc; __syncthreads();
  for (int off = 1; off < 256; off <<= 1) {
    float val = (t >= off) ? arr[t-off] : 0.f;
    __syncthreads();
    arr[t] += val;
    __syncthreads();
  }
  float c = (t > 0) ? arr[t-1] : 0.f;
  float av[8]; float lmax = -INFINITY;
  #pragma unroll
  for (int i2 = 0; i2 < 8; ++i2) {
    c += lv[i2];
    cs[h*S_LEN + base + i2] = c;
    float ai = igh[base + i2] - c;
    av[i2] = ai;
    a[h*S_LEN + base + i2] = ai;
    lmax = fmaxf(lmax, ai);
  }
  __syncthreads();
  arr[t] = lmax; __syncthreads();
  for (int off = 1; off < 256; off <<= 1) {
    float val = (t >= off) ? arr[t-off] : -INFINITY;
    __syncthreads();
    arr[t] = fmaxf(arr[t], val);
    __syncthreads();
  }
  float m = (t > 0) ? arr[t-1] : -INFINITY;
  #pragma unroll
  for (int i2 = 0; i2 < 8; ++i2) {
    m = fmaxf(m, av[i2]);
    M[h*S_LEN + base + i2] = m;
  }
}

// ---------------- Kernel 3: main causal tiled matmul + epilogue ----------------
// Block handles two Q-tiles (it, NT-1-it) for constant work (65 j-tiles total).
// Thread (r = t>>3, l8 = t&7): owns query row i0+r; scores j = l8+8*jj; output
// dims d = 4*l8 + 32*u + c (conflict-free V reads).
__global__ __launch_bounds__(256) void mlstm_main(
    const float* __restrict__ q, const float* __restrict__ k, const float* __restrict__ v,
    const float* __restrict__ cs, const float* __restrict__ a, const float* __restrict__ M,
    const float* __restrict__ out_w, float* __restrict__ out)
{
  __shared__ float Qs[QT][PAD];
  __shared__ float Ks[JT][PAD];
  __shared__ float Vs[JT][PAD];
  __shared__ float Cw[QT][33];
  __shared__ float wa_s[JT];

  const int bb = blockIdx.x;
  const int h = bb >> 5;     // / (NT/2)
  const int p = bb & 31;
  const int t = threadIdx.x;
  const int r = t >> 3;
  const int l8 = t & 7;

  for (int pass = 0; pass < 2; ++pass) {
    const int it = pass ? (NT-1-p) : p;
    const int i0 = it*QT;
    const int i  = i0 + r;
    const float Mi  = M[h*S_LEN + i];
    const float csi = cs[h*S_LEN + i];
    __syncthreads();  // previous pass fully done with LDS
    {
      const float4* src = (const float4*)(q + (size_t)(i0+r)*EDIM + h*DHEAD);
      float4* dst = (float4*)&Qs[r][0];
      #pragma unroll
      for (int u = 0; u < 4; ++u) dst[l8*4+u] = src[l8*4+u];
    }
    float acc[4][4];
    #pragma unroll
    for (int u = 0; u < 4; ++u) { acc[u][0]=acc[u][1]=acc[u][2]=acc[u][3]=0.f; }
    float rs = 0.f;

    for (int jt = 0; jt <= it; ++jt) {
      const int j0 = jt*JT;
      {
        const float4* ksrc = (const float4*)(k + (size_t)(j0+r)*EDIM + h*DHEAD);
        const float4* vsrc = (const float4*)(v + (size_t)(j0+r)*EDIM + h*DHEAD);
        float4* kd = (float4*)&Ks[r][0];
        float4* vd = (float4*)&Vs[r][0];
        #pragma unroll
        for (int u = 0; u < 4; ++u) { kd[l8*4+u] = ksrc[l8*4+u]; vd[l8*4+u] = vsrc[l8*4+u]; }
        if (t < JT) wa_s[t] = a[h*S_LEN + j0 + t];
      }
      __syncthreads();
      // ---- scores: 4 per thread, rows r, cols l8 + 8*jj ----
      float sc0=0.f, sc1=0.f, sc2=0.f, sc3=0.f;
      {
        const float4* qr = (const float4*)&Qs[r][0];
        const float4* k0 = (const float4*)&Ks[l8][0];
        const float4* k1 = (const float4*)&Ks[l8+8][0];
        const float4* k2 = (const float4*)&Ks[l8+16][0];
        const float4* k3 = (const float4*)&Ks[l8+24][0];
        #pragma unroll 8
        for (int d4 = 0; d4 < 32; ++d4) {
          const float4 qv = qr[d4];
          float4 kv;
          kv = k0[d4]; sc0 += qv.x*kv.x + qv.y*kv.y + qv.z*kv.z + qv.w*kv.w;
          kv = k1[d4]; sc1 += qv.x*kv.x + qv.y*kv.y + qv.z*kv.z + qv.w*kv.w;
          kv = k2[d4]; sc2 += qv.x*kv.x + qv.y*kv.y + qv.z*kv.z + qv.w*kv.w;
          kv = k3[d4]; sc3 += qv.x*kv.x + qv.y*kv.y + qv.z*kv.z + qv.w*kv.w;
        }
      }
      {
        const float scl = 0.08838834764831845f;  // 1/sqrt(128)
        float scv[4] = {sc0, sc1, sc2, sc3};
        float psum = 0.f;
        #pragma unroll
        for (int jj = 0; jj < 4; ++jj) {
          const int j = l8 + jj*8;
          const int gj = j0 + j;
          float cval = 0.f;
          if (gj <= i) cval = scv[jj]*scl*expf(wa_s[j] - Mi);
          Cw[r][j] = cval;
          psum += cval;
        }
        psum += __shfl_xor(psum, 1);
        psum += __shfl_xor(psum, 2);
        psum += __shfl_xor(psum, 4);
        rs += psum;
      }
      __syncthreads();
      // ---- PV: acc[u][c] over dims d = 4*l8 + 32*u + c ----
      for (int j = 0; j < JT; ++j) {
        const float cv = Cw[r][j];
        const float4* vr = (const float4*)&Vs[j][0];
        #pragma unroll
        for (int u = 0; u < 4; ++u) {
          const float4 vv = vr[l8 + u*8];
          acc[u][0] += cv*vv.x; acc[u][1] += cv*vv.y;
          acc[u][2] += cv*vv.z; acc[u][3] += cv*vv.w;
        }
      }
      __syncthreads();  // Ks/Vs/Cw reused next iteration
    }

    // ---- epilogue: normalizer + per-head LayerNorm ----
    const float norm = fmaxf(fabsf(rs), expf(-(csi + Mi))) + 1e-6f;
    const float inv = 1.0f / norm;
    float s1 = 0.f, s2 = 0.f;
    float hv[16];
    #pragma unroll
    for (int u = 0; u < 4; ++u)
      #pragma unroll
      for (int c2 = 0; c2 < 4; ++c2) {
        float x = acc[u][c2]*inv;
        hv[u*4+c2] = x; s1 += x; s2 += x*x;
      }
    s1 += __shfl_xor(s1,1); s1 += __shfl_xor(s1,2); s1 += __shfl_xor(s1,4);
    s2 += __shfl_xor(s2,1); s2 += __shfl_xor(s2,2); s2 += __shfl_xor(s2,4);
    const float mean = s1*(1.f/DHEAD);
    const float var  = s2*(1.f/DHEAD) - mean*mean;
    const float rstd = rsqrtf(var + 1e-5f);
    float* op = out + (size_t)i*EDIM + h*DHEAD;
    const float* ow = out_w + h*DHEAD;
    #pragma unroll
    for (int u = 0; u < 4; ++u) {
      const int d = l8*4 + u*32;
      float4 o;
      o.x = (hv[u*4+0]-mean)*rstd*ow[d+0];
      o.y = (hv[u*4+1]-mean)*rstd*ow[d+1];
      o.z = (hv[u*4+2]-mean)*rstd*ow[d+2];
      o.w = (hv[u*4+3]-mean)*rstd*ow[d+3];
      *((float4*)(op + d)) = o;
    }
  }
}

extern "C" void kernel_launch(void* const* d_in, const int* in_sizes, int n_in,
                              void* d_out, int out_size, void* d_ws, size_t ws_size,
                              hipStream_t stream) {
  const float* q  = (const float*)d_in[0];
  const float* k  = (const float*)d_in[1];
  const float* v  = (const float*)d_in[2];
  const float* iw = (const float*)d_in[3];
  const float* ib = (const float*)d_in[4];
  const float* fw = (const float*)d_in[5];
  const float* fb = (const float*)d_in[6];
  const float* ow = (const float*)d_in[7];
  float* out = (float*)d_out;
  float* ws = (float*)d_ws;
  float* ig = ws;
  float* fg = ws + 1*NHEAD*S_LEN;
  float* cs = ws + 2*NHEAD*S_LEN;
  float* aa = ws + 3*NHEAD*S_LEN;
  float* Mm = ws + 4*NHEAD*S_LEN;

  hipLaunchKernelGGL(gates_kernel, dim3(S_LEN), dim3(256), 0, stream,
                     q, k, v, iw, ib, fw, fb, ig, fg);
  hipLaunchKernelGGL(scan_kernel, dim3(NHEAD), dim3(256), 0, stream,
                     ig, fg, cs, aa, Mm);
  hipLaunchKernelGGL(mlstm_main, dim3(NHEAD*NT/2), dim3(256), 0, stream,
                     q, k, v, cs, aa, Mm, ow, out);
}

// Round 2
// 139.499 us; speedup vs baseline: 3.4544x; 3.4544x over previous
//
#include <hip/hip_runtime.h>
#include <hip/hip_bf16.h>
#include <math.h>

#define S_LEN 2048
#define EDIM  1024
#define NHEAD 8
#define DHEAD 128
#define QT    32
#define NT    64            // S_LEN/QT
#define SCL   0.08838834764831845f   // 1/sqrt(128)

typedef __bf16 bf16x8 __attribute__((ext_vector_type(8)));
typedef __bf16 bf16x2 __attribute__((ext_vector_type(2)));
typedef float  f32x16 __attribute__((ext_vector_type(16)));
typedef unsigned int u32x4 __attribute__((ext_vector_type(4)));

__device__ __forceinline__ unsigned pk2(float a, float b) {
  bf16x2 t; t[0] = (__bf16)a; t[1] = (__bf16)b;
  return __builtin_bit_cast(unsigned, t);
}
__device__ __forceinline__ void lane32_swap(unsigned &x, unsigned &y) {
  asm volatile("v_permlane32_swap_b32 %0, %1" : "+v"(x), "+v"(y));
}

// ---------------- Kernel 1: gate preactivations ----------------
__global__ __launch_bounds__(256) void gates_kernel(
    const float* __restrict__ q, const float* __restrict__ k, const float* __restrict__ v,
    const float* __restrict__ iw, const float* __restrict__ ib,
    const float* __restrict__ fw, const float* __restrict__ fb,
    float* __restrict__ ig, float* __restrict__ fg)
{
  __shared__ float gi[3*EDIM];
  const int s = blockIdx.x;
  const int t = threadIdx.x;
  const float4* q4 = (const float4*)(q + (size_t)s*EDIM);
  const float4* k4 = (const float4*)(k + (size_t)s*EDIM);
  const float4* v4 = (const float4*)(v + (size_t)s*EDIM);
  float4* g4 = (float4*)gi;
  g4[t]       = q4[t];
  g4[t + 256] = k4[t];
  g4[t + 512] = v4[t];
  __syncthreads();
  const int w = t >> 6, lane = t & 63;
  for (int c = w; c < 16; c += 4) {
    const int h = c & 7;
    const int gate = c >> 3;
    const float4* wr4 = (const float4*)(((gate ? fw : iw)) + (size_t)h*3*EDIM);
    float sum = 0.f;
    for (int e = lane; e < 768; e += 64) {
      const float4 wv = wr4[e];
      sum += gi[4*e]*wv.x + gi[4*e+1]*wv.y + gi[4*e+2]*wv.z + gi[4*e+3]*wv.w;
    }
    #pragma unroll
    for (int off = 32; off; off >>= 1) sum += __shfl_xor(sum, off);
    if (lane == 0) {
      if (gate) fg[h*S_LEN + s] = sum + fb[h];
      else      ig[h*S_LEN + s] = sum + ib[h];
    }
  }
}

// ---------------- Kernel 2: per-head scans ----------------
__global__ __launch_bounds__(256) void scan_kernel(
    const float* __restrict__ ig, const float* __restrict__ fg,
    float* __restrict__ cs, float* __restrict__ a, float* __restrict__ M)
{
  __shared__ float arr[256];
  const int h = blockIdx.x, t = threadIdx.x;
  const int base = t*8;
  const float* fgh = fg + h*S_LEN;
  const float* igh = ig + h*S_LEN;
  float lv[8];
  float loc = 0.f;
  #pragma unroll
  for (int i2 = 0; i2 < 8; ++i2) {
    float x = fgh[base + i2];
    float ls = fminf(x, 0.f) - log1pf(expf(-fabsf(x)));
    lv[i2] = ls; loc += ls;
  }
  arr[t] = loc; __syncthreads();
  for (int off = 1; off < 256; off <<= 1) {
    float val = (t >= off) ? arr[t-off] : 0.f;
    __syncthreads();
    arr[t] += val;
    __syncthreads();
  }
  float c = (t > 0) ? arr[t-1] : 0.f;
  float av[8]; float lmax = -INFINITY;
  #pragma unroll
  for (int i2 = 0; i2 < 8; ++i2) {
    c += lv[i2];
    cs[h*S_LEN + base + i2] = c;
    float ai = igh[base + i2] - c;
    av[i2] = ai;
    a[h*S_LEN + base + i2] = ai;
    lmax = fmaxf(lmax, ai);
  }
  __syncthreads();
  arr[t] = lmax; __syncthreads();
  for (int off = 1; off < 256; off <<= 1) {
    float val = (t >= off) ? arr[t-off] : -INFINITY;
    __syncthreads();
    arr[t] = fmaxf(arr[t], val);
    __syncthreads();
  }
  float m = (t > 0) ? arr[t-1] : -INFINITY;
  #pragma unroll
  for (int i2 = 0; i2 < 8; ++i2) {
    m = fmaxf(m, av[i2]);
    M[h*S_LEN + base + i2] = m;
  }
}

// ---------------- Kernel 3: MFMA flash-style main ----------------
// Block: 4 waves, handles Q-tile pair (p, 63-p) of one head.
// Per pass: each wave j-splits kv-tiles round-robin (no LDS in loop, no sync).
// S^T = mfma(A=K, B=Q*scl): lane holds col q=lane&31, rows j=crow(r,hi).
// P->bf16 A-frag via cvt_pk + permlane32_swap (T12). acc = mfma(P, V).
__global__ __launch_bounds__(256, 1) void mlstm_main(
    const float* __restrict__ q, const float* __restrict__ k, const float* __restrict__ v,
    const float* __restrict__ cs, const float* __restrict__ a, const float* __restrict__ M,
    const float* __restrict__ out_w, float* __restrict__ out)
{
  __shared__ float red[2][QT][DHEAD];   // 32 KB tree-reduction buffer
  __shared__ float rs_red[2][QT];

  const int bb  = blockIdx.x;
  const int h   = bb >> 5;
  const int p   = bb & 31;
  const int t   = threadIdx.x;
  const int w   = t >> 6;       // wave 0..3
  const int lane = t & 63;
  const int q32 = lane & 31;    // MFMA col index (q row within tile / d col / K row)
  const int hi  = lane >> 5;

  for (int pass = 0; pass < 2; ++pass) {
    const int it = pass ? (NT-1-p) : p;
    const int i0 = it*QT;
    const int iq = i0 + q32;
    const float Mi = M[h*S_LEN + iq];

    // Q B-fragments (scale folded in), kept in VGPRs for the whole pass
    bf16x8 qf[8];
    {
      const float* qrow = q + (size_t)iq*EDIM + h*DHEAD + hi*8;
      #pragma unroll
      for (int ks = 0; ks < 8; ++ks) {
        bf16x8 f;
        #pragma unroll
        for (int e = 0; e < 8; ++e) f[e] = (__bf16)(qrow[ks*16 + e]*SCL);
        qf[ks] = f;
      }
    }
    f32x16 acc[4];
    #pragma unroll
    for (int db = 0; db < 4; ++db)
      #pragma unroll
      for (int r = 0; r < 16; ++r) acc[db][r] = 0.f;
    float rs = 0.f;

    for (int jt = w; jt <= it; jt += 4) {
      const int j0 = jt*QT;
      // ---- QK^T (swapped): st[j][q] ----
      f32x16 st;
      #pragma unroll
      for (int r = 0; r < 16; ++r) st[r] = 0.f;
      {
        const float* krow = k + (size_t)(j0 + q32)*EDIM + h*DHEAD + hi*8;
        #pragma unroll
        for (int ks = 0; ks < 8; ++ks) {
          bf16x8 f;
          #pragma unroll
          for (int e = 0; e < 8; ++e) f[e] = (__bf16)krow[ks*16 + e];
          st = __builtin_amdgcn_mfma_f32_32x32x16_bf16(f, qf[ks], st, 0, 0, 0);
        }
      }
      // ---- weight by exp(a[j]-M[i]), causal mask on diagonal tile ----
      const float wa = a[h*S_LEN + j0 + q32];
      const bool diag = (jt == it);
      float pw[16];
      float rsl = 0.f;
      #pragma unroll
      for (int r = 0; r < 16; ++r) {
        const int jl = (r&3) + 8*(r>>2) + 4*hi;  // C-layout row = local j
        const float av = __shfl(wa, jl);
        float cv = st[r] * __expf(av - Mi);
        if (diag && jl > q32) cv = 0.f;
        pw[r] = cv; rsl += cv;
      }
      rs += rsl;
      // ---- P -> bf16 A-fragments (cvt_pk + permlane32_swap) ----
      unsigned w00 = pk2(pw[0],pw[1]),   w02 = pk2(pw[4],pw[5]);
      unsigned w01 = pk2(pw[2],pw[3]),   w03 = pk2(pw[6],pw[7]);
      unsigned w10 = pk2(pw[8],pw[9]),   w12 = pk2(pw[12],pw[13]);
      unsigned w11 = pk2(pw[10],pw[11]), w13 = pk2(pw[14],pw[15]);
      lane32_swap(w00, w02); lane32_swap(w01, w03);
      lane32_swap(w10, w12); lane32_swap(w11, w13);
      u32x4 a0v; a0v[0]=w00; a0v[1]=w01; a0v[2]=w02; a0v[3]=w03;
      u32x4 a1v; a1v[0]=w10; a1v[1]=w11; a1v[2]=w12; a1v[3]=w13;
      const bf16x8 pa0 = __builtin_bit_cast(bf16x8, a0v);
      const bf16x8 pa1 = __builtin_bit_cast(bf16x8, a1v);
      // ---- PV: acc[db] += P * V ----
      {
        const float* vb = v + (size_t)(j0 + hi*8)*EDIM + h*DHEAD + q32;
        #pragma unroll
        for (int db = 0; db < 4; ++db) {
          #pragma unroll
          for (int ks = 0; ks < 2; ++ks) {
            bf16x8 vf;
            #pragma unroll
            for (int e = 0; e < 8; ++e)
              vf[e] = (__bf16)vb[(size_t)(ks*16 + e)*EDIM + db*32];
            acc[db] = __builtin_amdgcn_mfma_f32_32x32x16_bf16(
                        ks ? pa1 : pa0, vf, acc[db], 0, 0, 0);
          }
        }
      }
    }

    // combine hi-halves of row sums (lanes l and l+32 share q-row)
    rs += __shfl_xor(rs, 32);

    // ---- 2-step cross-wave tree reduction in LDS ----
    if (w >= 2) {
      #pragma unroll
      for (int db = 0; db < 4; ++db)
        #pragma unroll
        for (int r = 0; r < 16; ++r) {
          const int row = (r&3) + 8*(r>>2) + 4*hi;
          red[w-2][row][db*32 + q32] = acc[db][r];
        }
      if (lane < 32) rs_red[w-2][q32] = rs;
    }
    __syncthreads();
    if (w < 2) {
      #pragma unroll
      for (int db = 0; db < 4; ++db)
        #pragma unroll
        for (int r = 0; r < 16; ++r) {
          const int row = (r&3) + 8*(r>>2) + 4*hi;
          acc[db][r] += red[w][row][db*32 + q32];
        }
      rs += rs_red[w][q32];
      #pragma unroll
      for (int db = 0; db < 4; ++db)
        #pragma unroll
        for (int r = 0; r < 16; ++r) {
          const int row = (r&3) + 8*(r>>2) + 4*hi;
          red[w][row][db*32 + q32] = acc[db][r];
        }
      if (lane < 32) rs_red[w][q32] = rs;
    }
    __syncthreads();

    // ---- epilogue: normalizer + per-head LayerNorm ----
    {
      const int r2 = t >> 3;
      const int l8 = t & 7;
      const int i  = i0 + r2;
      const float rst = rs_red[0][r2] + rs_red[1][r2];
      const float csi = cs[h*S_LEN + i];
      const float Mi2 = M[h*S_LEN + i];
      const float norm = fmaxf(fabsf(rst), __expf(-(csi + Mi2))) + 1e-6f;
      const float inv = 1.0f / norm;
      float hv[16]; float s1 = 0.f, s2 = 0.f;
      #pragma unroll
      for (int u = 0; u < 4; ++u) {
        const int d = l8*4 + u*32;
        #pragma unroll
        for (int c2 = 0; c2 < 4; ++c2) {
          float x = (red[0][r2][d+c2] + red[1][r2][d+c2]) * inv;
          hv[u*4+c2] = x; s1 += x; s2 += x*x;
        }
      }
      s1 += __shfl_xor(s1,1); s1 += __shfl_xor(s1,2); s1 += __shfl_xor(s1,4);
      s2 += __shfl_xor(s2,1); s2 += __shfl_xor(s2,2); s2 += __shfl_xor(s2,4);
      const float mean = s1*(1.f/DHEAD);
      const float var  = s2*(1.f/DHEAD) - mean*mean;
      const float rstd = rsqrtf(var + 1e-5f);
      float* op = out + (size_t)i*EDIM + h*DHEAD;
      const float* ow = out_w + h*DHEAD;
      #pragma unroll
      for (int u = 0; u < 4; ++u) {
        const int d = l8*4 + u*32;
        float4 o;
        o.x = (hv[u*4+0]-mean)*rstd*ow[d+0];
        o.y = (hv[u*4+1]-mean)*rstd*ow[d+1];
        o.z = (hv[u*4+2]-mean)*rstd*ow[d+2];
        o.w = (hv[u*4+3]-mean)*rstd*ow[d+3];
        *((float4*)(op + d)) = o;
      }
    }
    __syncthreads();  // red reused by next pass
  }
}

extern "C" void kernel_launch(void* const* d_in, const int* in_sizes, int n_in,
                              void* d_out, int out_size, void* d_ws, size_t ws_size,
                              hipStream_t stream) {
  const float* q  = (const float*)d_in[0];
  const float* k  = (const float*)d_in[1];
  const float* v  = (const float*)d_in[2];
  const float* iw = (const float*)d_in[3];
  const float* ib = (const float*)d_in[4];
  const float* fw = (const float*)d_in[5];
  const float* fb = (const float*)d_in[6];
  const float* ow = (const float*)d_in[7];
  float* out = (float*)d_out;
  float* ws = (float*)d_ws;
  float* ig = ws;
  float* fg = ws + 1*NHEAD*S_LEN;
  float* cs = ws + 2*NHEAD*S_LEN;
  float* aa = ws + 3*NHEAD*S_LEN;
  float* Mm = ws + 4*NHEAD*S_LEN;

  hipLaunchKernelGGL(gates_kernel, dim3(S_LEN), dim3(256), 0, stream,
                     q, k, v, iw, ib, fw, fb, ig, fg);
  hipLaunchKernelGGL(scan_kernel, dim3(NHEAD), dim3(256), 0, stream,
                     ig, fg, cs, aa, Mm);
  hipLaunchKernelGGL(mlstm_main, dim3(NHEAD*NT/2), dim3(256), 0, stream,
                     q, k, v, cs, aa, Mm, ow, out);
}

// Round 3
// 69.239 us; speedup vs baseline: 6.9598x; 2.0147x over previous
//
#include <hip/hip_runtime.h>
#include <hip/hip_bf16.h>
#include <math.h>

#define S_LEN 2048
#define EDIM  1024
#define NHEAD 8
#define DHEAD 128
#define QT    32
#define NT    64            // S_LEN/QT
#define SCL   0.08838834764831845f   // 1/sqrt(128)

typedef __bf16 bf16x8 __attribute__((ext_vector_type(8)));
typedef __bf16 bf16x2 __attribute__((ext_vector_type(2)));
typedef float  f32x16 __attribute__((ext_vector_type(16)));
typedef unsigned int u32x4 __attribute__((ext_vector_type(4)));

__device__ __forceinline__ unsigned pk2(float a, float b) {
  bf16x2 t; t[0] = (__bf16)a; t[1] = (__bf16)b;
  return __builtin_bit_cast(unsigned, t);
}
__device__ __forceinline__ unsigned short bfb(float x) {
  return __builtin_bit_cast(unsigned short, (__bf16)x);
}
__device__ __forceinline__ void lane32_swap(unsigned &x, unsigned &y) {
  asm volatile("v_permlane32_swap_b32 %0, %1" : "+v"(x), "+v"(y));
}

// ---------------- Kernel 1: gates + bf16 pack (Qb,Kb row-major; Vt transposed) ----
// Block = 4 s-rows. Weights register-blocked 4 outs x 4 rows per wave.
__global__ __launch_bounds__(256) void gates_pack_kernel(
    const float* __restrict__ q, const float* __restrict__ k, const float* __restrict__ v,
    const float* __restrict__ iw, const float* __restrict__ ib,
    const float* __restrict__ fw, const float* __restrict__ fb,
    float* __restrict__ ig, float* __restrict__ fg,
    unsigned short* __restrict__ Qb, unsigned short* __restrict__ Kb,
    unsigned short* __restrict__ Vt)
{
  __shared__ float gl[4][3076];
  const int s0 = blockIdx.x * 4;
  const int t = threadIdx.x;
  // phase A: stage 4 rows of concat(q,k,v)
  #pragma unroll
  for (int sr = 0; sr < 4; ++sr) {
    const float4* qs = (const float4*)(q + (size_t)(s0+sr)*EDIM);
    const float4* ks = (const float4*)(k + (size_t)(s0+sr)*EDIM);
    const float4* vs = (const float4*)(v + (size_t)(s0+sr)*EDIM);
    float4* dst = (float4*)&gl[sr][0];
    dst[t]       = qs[t];
    dst[t + 256] = ks[t];
    dst[t + 512] = vs[t];
  }
  __syncthreads();
  // phase B: dots. wave w -> outputs c in {w, w+4, w+8, w+12}; lanes split e.
  const int w = t >> 6, lane = t & 63;
  float sum[4][4];
  #pragma unroll
  for (int ci = 0; ci < 4; ++ci)
    #pragma unroll
    for (int sr = 0; sr < 4; ++sr) sum[ci][sr] = 0.f;
  #pragma unroll 2
  for (int ch = 0; ch < 12; ++ch) {
    float4 wv[4];
    #pragma unroll
    for (int ci = 0; ci < 4; ++ci) {
      const int c = w + 4*ci;
      const float* wr = (c >= 8 ? fw : iw) + (size_t)(c & 7)*3*EDIM;
      wv[ci] = ((const float4*)wr)[ch*64 + lane];
    }
    #pragma unroll
    for (int sr = 0; sr < 4; ++sr) {
      const float4 g = ((const float4*)&gl[sr][0])[ch*64 + lane];
      #pragma unroll
      for (int ci = 0; ci < 4; ++ci) {
        sum[ci][sr] += g.x*wv[ci].x + g.y*wv[ci].y + g.z*wv[ci].z + g.w*wv[ci].w;
      }
    }
  }
  #pragma unroll
  for (int ci = 0; ci < 4; ++ci)
    #pragma unroll
    for (int sr = 0; sr < 4; ++sr) {
      float s = sum[ci][sr];
      #pragma unroll
      for (int off = 32; off; off >>= 1) s += __shfl_xor(s, off);
      if (lane == 0) {
        const int c = w + 4*ci;
        const int hh = c & 7;
        if (c >= 8) fg[hh*S_LEN + s0 + sr] = s + fb[hh];
        else        ig[hh*S_LEN + s0 + sr] = s + ib[hh];
      }
    }
  // phase D: pack Qb (x SCL) and Kb rows (bf16, coalesced)
  #pragma unroll
  for (int sr = 0; sr < 4; ++sr) {
    const float4 qv = ((const float4*)&gl[sr][0])[t];
    const float4 kv = ((const float4*)&gl[sr][0])[t + 256];
    ushort4 qo, ko;
    qo.x = bfb(qv.x*SCL); qo.y = bfb(qv.y*SCL); qo.z = bfb(qv.z*SCL); qo.w = bfb(qv.w*SCL);
    ko.x = bfb(kv.x); ko.y = bfb(kv.y); ko.z = bfb(kv.z); ko.w = bfb(kv.w);
    ((ushort4*)(Qb + (size_t)(s0+sr)*EDIM))[t] = qo;
    ((ushort4*)(Kb + (size_t)(s0+sr)*EDIM))[t] = ko;
  }
  // phase E: pack Vt[e][s] transposed (4 s-values per store)
  #pragma unroll
  for (int u = 0; u < 4; ++u) {
    const int dd = t + u*256;
    ushort4 o;
    o.x = bfb(gl[0][2048 + dd]);
    o.y = bfb(gl[1][2048 + dd]);
    o.z = bfb(gl[2][2048 + dd]);
    o.w = bfb(gl[3][2048 + dd]);
    *(ushort4*)(Vt + (size_t)dd*S_LEN + s0) = o;
  }
}

// ---------------- Kernel 2: per-head scans ----------------
__global__ __launch_bounds__(256) void scan_kernel(
    const float* __restrict__ ig, const float* __restrict__ fg,
    float* __restrict__ cs, float* __restrict__ a, float* __restrict__ M)
{
  __shared__ float arr[256];
  const int h = blockIdx.x, t = threadIdx.x;
  const int base = t*8;
  const float* fgh = fg + h*S_LEN;
  const float* igh = ig + h*S_LEN;
  float lv[8];
  float loc = 0.f;
  #pragma unroll
  for (int i2 = 0; i2 < 8; ++i2) {
    float x = fgh[base + i2];
    float ls = fminf(x, 0.f) - log1pf(expf(-fabsf(x)));
    lv[i2] = ls; loc += ls;
  }
  arr[t] = loc; __syncthreads();
  for (int off = 1; off < 256; off <<= 1) {
    float val = (t >= off) ? arr[t-off] : 0.f;
    __syncthreads();
    arr[t] += val;
    __syncthreads();
  }
  float c = (t > 0) ? arr[t-1] : 0.f;
  float av[8]; float lmax = -INFINITY;
  #pragma unroll
  for (int i2 = 0; i2 < 8; ++i2) {
    c += lv[i2];
    cs[h*S_LEN + base + i2] = c;
    float ai = igh[base + i2] - c;
    av[i2] = ai;
    a[h*S_LEN + base + i2] = ai;
    lmax = fmaxf(lmax, ai);
  }
  __syncthreads();
  arr[t] = lmax; __syncthreads();
  for (int off = 1; off < 256; off <<= 1) {
    float val = (t >= off) ? arr[t-off] : -INFINITY;
    __syncthreads();
    arr[t] = fmaxf(arr[t], val);
    __syncthreads();
  }
  float m = (t > 0) ? arr[t-1] : -INFINITY;
  #pragma unroll
  for (int i2 = 0; i2 < 8; ++i2) {
    m = fmaxf(m, av[i2]);
    M[h*S_LEN + base + i2] = m;
  }
}

// ---------------- Kernel 3: MFMA flash-style main (bf16 packed operands) ------
// head = bb&7 -> all 32 blocks of a head on one XCD (L2-resident K/V).
// 2x-unrolled j-loop with K-fragment + a[] prefetch; V loads at body top.
__global__ __launch_bounds__(256, 1) void mlstm_main(
    const unsigned short* __restrict__ Qb, const unsigned short* __restrict__ Kb,
    const unsigned short* __restrict__ Vt,
    const float* __restrict__ cs, const float* __restrict__ a, const float* __restrict__ M,
    const float* __restrict__ out_w, float* __restrict__ out)
{
  __shared__ float red[2][QT][DHEAD];
  __shared__ float rs_red[2][QT];

  const int bb  = blockIdx.x;
  const int h   = bb & 7;       // XCD-locality: head h -> XCD h
  const int p   = bb >> 3;      // 0..31
  const int t   = threadIdx.x;
  const int w   = t >> 6;
  const int lane = t & 63;
  const int q32 = lane & 31;
  const int hi  = lane >> 5;

  const bf16x8* QB8 = (const bf16x8*)Qb;
  const bf16x8* KB8 = (const bf16x8*)Kb;
  const bf16x8* VT8 = (const bf16x8*)Vt;
  const float* ah = a + h*S_LEN;

  for (int pass = 0; pass < 2; ++pass) {
    const int it = pass ? (NT-1-p) : p;
    const int i0 = it*QT;
    const int iq = i0 + q32;
    const float Mi = M[h*S_LEN + iq];

    bf16x8 qf[8];
    {
      const size_t qb = (size_t)iq*128 + h*16 + hi;
      #pragma unroll
      for (int ks = 0; ks < 8; ++ks) qf[ks] = QB8[qb + 2*ks];
    }
    f32x16 acc[4];
    #pragma unroll
    for (int db = 0; db < 4; ++db)
      #pragma unroll
      for (int r = 0; r < 16; ++r) acc[db][r] = 0.f;
    float rs = 0.f;

    bf16x8 kA[8], kB[8];
    float avA = 0.f, avB = 0.f;

    #define LOADK(BUF, AV, JT) do {                                     \
        const size_t kb_ = (size_t)((JT)*QT + q32)*128 + h*16 + hi;     \
        _Pragma("unroll")                                               \
        for (int ks_ = 0; ks_ < 8; ++ks_) BUF[ks_] = KB8[kb_ + 2*ks_];  \
        AV = ah[(JT)*QT + q32];                                         \
      } while (0)

    #define BODY(KF, WA, JT) do {                                       \
        const int j0_ = (JT)*QT;                                        \
        bf16x8 vf[4][2];                                                \
        _Pragma("unroll")                                               \
        for (int db_ = 0; db_ < 4; ++db_) {                             \
          const size_t vb_ = (size_t)(h*128 + db_*32 + q32)*256 + (j0_>>3) + hi; \
          vf[db_][0] = VT8[vb_];                                        \
          vf[db_][1] = VT8[vb_ + 2];                                    \
        }                                                               \
        f32x16 st0, st1;                                                \
        _Pragma("unroll")                                               \
        for (int r_ = 0; r_ < 16; ++r_) { st0[r_] = 0.f; st1[r_] = 0.f; } \
        _Pragma("unroll")                                               \
        for (int ks_ = 0; ks_ < 4; ++ks_) {                             \
          st0 = __builtin_amdgcn_mfma_f32_32x32x16_bf16(KF[2*ks_],   qf[2*ks_],   st0, 0, 0, 0); \
          st1 = __builtin_amdgcn_mfma_f32_32x32x16_bf16(KF[2*ks_+1], qf[2*ks_+1], st1, 0, 0, 0); \
        }                                                               \
        const bool diag_ = ((JT) == it);                                \
        float pw[16]; float rsl_ = 0.f;                                 \
        _Pragma("unroll")                                               \
        for (int r_ = 0; r_ < 16; ++r_) {                               \
          const int jl_ = (r_&3) + 8*(r_>>2) + 4*hi;                    \
          const float av_ = __shfl((WA), jl_);                          \
          float cv_ = (st0[r_] + st1[r_]) * __expf(av_ - Mi);           \
          if (diag_ && jl_ > q32) cv_ = 0.f;                            \
          pw[r_] = cv_; rsl_ += cv_;                                    \
        }                                                               \
        rs += rsl_;                                                     \
        unsigned w00 = pk2(pw[0],pw[1]),   w02 = pk2(pw[4],pw[5]);      \
        unsigned w01 = pk2(pw[2],pw[3]),   w03 = pk2(pw[6],pw[7]);      \
        unsigned w10 = pk2(pw[8],pw[9]),   w12 = pk2(pw[12],pw[13]);    \
        unsigned w11 = pk2(pw[10],pw[11]), w13 = pk2(pw[14],pw[15]);    \
        lane32_swap(w00, w02); lane32_swap(w01, w03);                   \
        lane32_swap(w10, w12); lane32_swap(w11, w13);                   \
        u32x4 a0v; a0v[0]=w00; a0v[1]=w01; a0v[2]=w02; a0v[3]=w03;      \
        u32x4 a1v; a1v[0]=w10; a1v[1]=w11; a1v[2]=w12; a1v[3]=w13;      \
        const bf16x8 pa0 = __builtin_bit_cast(bf16x8, a0v);             \
        const bf16x8 pa1 = __builtin_bit_cast(bf16x8, a1v);             \
        _Pragma("unroll")                                               \
        for (int db_ = 0; db_ < 4; ++db_) {                             \
          acc[db_] = __builtin_amdgcn_mfma_f32_32x32x16_bf16(pa0, vf[db_][0], acc[db_], 0, 0, 0); \
          acc[db_] = __builtin_amdgcn_mfma_f32_32x32x16_bf16(pa1, vf[db_][1], acc[db_], 0, 0, 0); \
        }                                                               \
      } while (0)

    int jt = w;
    if (jt <= it) LOADK(kA, avA, jt);
    while (jt <= it) {
      int nx = jt + 4;
      if (nx <= it) LOADK(kB, avB, nx);
      BODY(kA, avA, jt);
      jt = nx;
      if (jt > it) break;
      nx = jt + 4;
      if (nx <= it) LOADK(kA, avA, nx);
      BODY(kB, avB, jt);
      jt = nx;
    }
    #undef LOADK
    #undef BODY

    rs += __shfl_xor(rs, 32);

    // ---- 2-step cross-wave tree reduction in LDS ----
    if (w >= 2) {
      #pragma unroll
      for (int db = 0; db < 4; ++db)
        #pragma unroll
        for (int r = 0; r < 16; ++r) {
          const int row = (r&3) + 8*(r>>2) + 4*hi;
          red[w-2][row][db*32 + q32] = acc[db][r];
        }
      if (lane < 32) rs_red[w-2][q32] = rs;
    }
    __syncthreads();
    if (w < 2) {
      #pragma unroll
      for (int db = 0; db < 4; ++db)
        #pragma unroll
        for (int r = 0; r < 16; ++r) {
          const int row = (r&3) + 8*(r>>2) + 4*hi;
          acc[db][r] += red[w][row][db*32 + q32];
        }
      rs += rs_red[w][q32];
      #pragma unroll
      for (int db = 0; db < 4; ++db)
        #pragma unroll
        for (int r = 0; r < 16; ++r) {
          const int row = (r&3) + 8*(r>>2) + 4*hi;
          red[w][row][db*32 + q32] = acc[db][r];
        }
      if (lane < 32) rs_red[w][q32] = rs;
    }
    __syncthreads();

    // ---- epilogue: normalizer + per-head LayerNorm ----
    {
      const int r2 = t >> 3;
      const int l8 = t & 7;
      const int i  = i0 + r2;
      const float rst = rs_red[0][r2] + rs_red[1][r2];
      const float csi = cs[h*S_LEN + i];
      const float Mi2 = M[h*S_LEN + i];
      const float norm = fmaxf(fabsf(rst), __expf(-(csi + Mi2))) + 1e-6f;
      const float inv = 1.0f / norm;
      float hv[16]; float s1 = 0.f, s2 = 0.f;
      #pragma unroll
      for (int u = 0; u < 4; ++u) {
        const int d = l8*4 + u*32;
        #pragma unroll
        for (int c2 = 0; c2 < 4; ++c2) {
          float x = (red[0][r2][d+c2] + red[1][r2][d+c2]) * inv;
          hv[u*4+c2] = x; s1 += x; s2 += x*x;
        }
      }
      s1 += __shfl_xor(s1,1); s1 += __shfl_xor(s1,2); s1 += __shfl_xor(s1,4);
      s2 += __shfl_xor(s2,1); s2 += __shfl_xor(s2,2); s2 += __shfl_xor(s2,4);
      const float mean = s1*(1.f/DHEAD);
      const float var  = s2*(1.f/DHEAD) - mean*mean;
      const float rstd = rsqrtf(var + 1e-5f);
      float* op = out + (size_t)i*EDIM + h*DHEAD;
      const float* ow = out_w + h*DHEAD;
      #pragma unroll
      for (int u = 0; u < 4; ++u) {
        const int d = l8*4 + u*32;
        float4 o;
        o.x = (hv[u*4+0]-mean)*rstd*ow[d+0];
        o.y = (hv[u*4+1]-mean)*rstd*ow[d+1];
        o.z = (hv[u*4+2]-mean)*rstd*ow[d+2];
        o.w = (hv[u*4+3]-mean)*rstd*ow[d+3];
        *((float4*)(op + d)) = o;
      }
    }
    __syncthreads();
  }
}

extern "C" void kernel_launch(void* const* d_in, const int* in_sizes, int n_in,
                              void* d_out, int out_size, void* d_ws, size_t ws_size,
                              hipStream_t stream) {
  const float* q  = (const float*)d_in[0];
  const float* k  = (const float*)d_in[1];
  const float* v  = (const float*)d_in[2];
  const float* iw = (const float*)d_in[3];
  const float* ib = (const float*)d_in[4];
  const float* fw = (const float*)d_in[5];
  const float* fb = (const float*)d_in[6];
  const float* ow = (const float*)d_in[7];
  float* out = (float*)d_out;
  float* ws = (float*)d_ws;
  float* ig = ws;
  float* fg = ws + 1*NHEAD*S_LEN;
  float* cs = ws + 2*NHEAD*S_LEN;
  float* aa = ws + 3*NHEAD*S_LEN;
  float* Mm = ws + 4*NHEAD*S_LEN;
  unsigned short* Qb = (unsigned short*)(ws + 5*NHEAD*S_LEN);
  unsigned short* Kb = Qb + (size_t)S_LEN*EDIM;
  unsigned short* Vt = Kb + (size_t)S_LEN*EDIM;

  hipLaunchKernelGGL(gates_pack_kernel, dim3(S_LEN/4), dim3(256), 0, stream,
                     q, k, v, iw, ib, fw, fb, ig, fg, Qb, Kb, Vt);
  hipLaunchKernelGGL(scan_kernel, dim3(NHEAD), dim3(256), 0, stream,
                     ig, fg, cs, aa, Mm);
  hipLaunchKernelGGL(mlstm_main, dim3(NHEAD*NT/2), dim3(256), 0, stream,
                     Qb, Kb, Vt, cs, aa, Mm, ow, out);
}

// Round 4
// 57.117 us; speedup vs baseline: 8.4369x; 1.2122x over previous
//
#include <hip/hip_runtime.h>
#include <hip/hip_bf16.h>
#include <math.h>

#define S_LEN 2048
#define EDIM  1024
#define NHEAD 8
#define DHEAD 128
#define QT    32
#define NT    64            // S_LEN/QT
#define SCL   0.08838834764831845f   // 1/sqrt(128)

typedef __bf16 bf16x8 __attribute__((ext_vector_type(8)));
typedef __bf16 bf16x2 __attribute__((ext_vector_type(2)));
typedef float  f32x16 __attribute__((ext_vector_type(16)));
typedef unsigned int u32x4 __attribute__((ext_vector_type(4)));

__device__ __forceinline__ unsigned pk2(float a, float b) {
  bf16x2 t; t[0] = (__bf16)a; t[1] = (__bf16)b;
  return __builtin_bit_cast(unsigned, t);
}
__device__ __forceinline__ unsigned short bfb(float x) {
  return __builtin_bit_cast(unsigned short, (__bf16)x);
}
__device__ __forceinline__ void lane32_swap(unsigned &x, unsigned &y) {
  asm volatile("v_permlane32_swap_b32 %0, %1" : "+v"(x), "+v"(y));
}

// ---------------- Kernel 1: gates + fragment-order bf16 pack ----------------
// Block = 8 s-rows (one V e-octet). Packs Qp/Kp/Vp so main-kernel fragment
// loads are single coalesced 1KB dwordx4 per (wave, ks).
//   Qp/Kp entry(h,tile,ks,l)      : row tile*32+(l&31), elems h*128+(l>>5)*8+ks*16+e
//   Vp entry(h,tile,ksv,db,l)     : col h*128+db*32+(l&31), rows tile*32+(l>>5)*8+ksv*16+e
__global__ __launch_bounds__(256) void gates_pack_kernel(
    const float* __restrict__ q, const float* __restrict__ k, const float* __restrict__ v,
    const float* __restrict__ iw, const float* __restrict__ ib,
    const float* __restrict__ fw, const float* __restrict__ fb,
    float* __restrict__ ig, float* __restrict__ fg,
    unsigned short* __restrict__ Qp, unsigned short* __restrict__ Kp,
    unsigned short* __restrict__ Vp)
{
  __shared__ float gl[8][3072];
  const int s0 = blockIdx.x * 8;
  const int t = threadIdx.x;
  const int w = t >> 6, lane = t & 63;
  // phase A: stage 8 rows of concat(q,k,v)
  #pragma unroll
  for (int rr = 0; rr < 8; ++rr) {
    const float4* qs = (const float4*)(q + (size_t)(s0+rr)*EDIM);
    const float4* ks = (const float4*)(k + (size_t)(s0+rr)*EDIM);
    const float4* vs = (const float4*)(v + (size_t)(s0+rr)*EDIM);
    float4* dst = (float4*)&gl[rr][0];
    dst[t]       = qs[t];
    dst[t + 256] = ks[t];
    dst[t + 512] = vs[t];
  }
  __syncthreads();
  // phase B: dots. wave w -> outputs c in {w, w+4, w+8, w+12}, 8 rows each.
  float sum[4][8];
  #pragma unroll
  for (int ci = 0; ci < 4; ++ci)
    #pragma unroll
    for (int rr = 0; rr < 8; ++rr) sum[ci][rr] = 0.f;
  for (int ch = 0; ch < 12; ++ch) {
    float4 wv[4];
    #pragma unroll
    for (int ci = 0; ci < 4; ++ci) {
      const int c = w + 4*ci;
      const float* wr = (c >= 8 ? fw : iw) + (size_t)(c & 7)*3*EDIM;
      wv[ci] = ((const float4*)wr)[ch*64 + lane];
    }
    #pragma unroll
    for (int rr = 0; rr < 8; ++rr) {
      const float4 g = ((const float4*)&gl[rr][0])[ch*64 + lane];
      #pragma unroll
      for (int ci = 0; ci < 4; ++ci)
        sum[ci][rr] += g.x*wv[ci].x + g.y*wv[ci].y + g.z*wv[ci].z + g.w*wv[ci].w;
    }
  }
  #pragma unroll
  for (int ci = 0; ci < 4; ++ci)
    #pragma unroll
    for (int rr = 0; rr < 8; ++rr) {
      float s = sum[ci][rr];
      #pragma unroll
      for (int off = 32; off; off >>= 1) s += __shfl_xor(s, off);
      if (lane == 0) {
        const int c = w + 4*ci;
        const int hh = c & 7;
        if (c >= 8) fg[hh*S_LEN + s0 + rr] = s + fb[hh];
        else        ig[hh*S_LEN + s0 + rr] = s + ib[hh];
      }
    }
  // phase C: pack Q (xSCL) and K. thread t owns elems 4t..4t+3 of each row.
  {
    const int hh = t >> 5;
    const int ks = (t >> 2) & 7;
    const int hi = (t >> 1) & 1;
    const int half = (t & 1);           // 8B half within 16B entry
    const int jt = s0 >> 5;
    #pragma unroll
    for (int rr = 0; rr < 8; ++rr) {
      const int l31 = (s0 & 31) + rr;
      const size_t idx16 = ((size_t)(hh*64 + jt)*8 + ks)*64 + hi*32 + l31;
      const float4 qv = ((const float4*)&gl[rr][0])[t];
      const float4 kv = ((const float4*)&gl[rr][0])[t + 256];
      ushort4 qo, ko;
      qo.x = bfb(qv.x*SCL); qo.y = bfb(qv.y*SCL); qo.z = bfb(qv.z*SCL); qo.w = bfb(qv.w*SCL);
      ko.x = bfb(kv.x); ko.y = bfb(kv.y); ko.z = bfb(kv.z); ko.w = bfb(kv.w);
      *(ushort4*)(Qp + idx16*8 + half*4) = qo;
      *(ushort4*)(Kp + idx16*8 + half*4) = ko;
    }
  }
  // phase D: pack V (transposed). Block covers one e-octet (8 rows).
  {
    const int hh  = t >> 5;
    const int c31 = t & 31;
    const int jt  = s0 >> 5;
    const int o   = (s0 & 31) >> 3;     // octet index within tile
    const int hiv = o & 1, ksv = o >> 1;
    #pragma unroll
    for (int db = 0; db < 4; ++db) {
      const int col = hh*128 + db*32 + c31;
      bf16x8 e;
      #pragma unroll
      for (int rr = 0; rr < 8; ++rr) e[rr] = (__bf16)gl[rr][2048 + col];
      const size_t idx16 = (((size_t)(hh*64 + jt)*2 + ksv)*4 + db)*64 + hiv*32 + c31;
      *(bf16x8*)(Vp + idx16*8) = e;
    }
  }
}

// ---------------- Kernel 2: per-head scans (shfl-based, 2 barriers) ---------
__global__ __launch_bounds__(256) void scan_kernel(
    const float* __restrict__ ig, const float* __restrict__ fg,
    float* __restrict__ cs, float* __restrict__ a, float* __restrict__ M)
{
  __shared__ float wsum[4];
  __shared__ float wmax[4];
  const int h = blockIdx.x, t = threadIdx.x;
  const int w = t >> 6, lane = t & 63;
  const int base = t*8;
  const float* fgh = fg + h*S_LEN;
  const float* igh = ig + h*S_LEN;
  float lv[8];
  float loc = 0.f;
  #pragma unroll
  for (int i2 = 0; i2 < 8; ++i2) {
    float x = fgh[base + i2];
    float ls = fminf(x, 0.f) - log1pf(expf(-fabsf(x)));
    lv[i2] = ls; loc += ls;
  }
  float sc = loc;
  #pragma unroll
  for (int off = 1; off < 64; off <<= 1) {
    float u = __shfl_up(sc, off);
    sc += (lane >= off) ? u : 0.f;
  }
  if (lane == 63) wsum[w] = sc;
  __syncthreads();
  float prefix = 0.f;
  #pragma unroll
  for (int ww = 0; ww < 4; ++ww) if (ww < w) prefix += wsum[ww];
  float c = prefix + sc - loc;  // exclusive prefix for this thread
  float av[8]; float lmax = -INFINITY;
  #pragma unroll
  for (int i2 = 0; i2 < 8; ++i2) {
    c += lv[i2];
    cs[h*S_LEN + base + i2] = c;
    float ai = igh[base + i2] - c;
    av[i2] = ai;
    a[h*S_LEN + base + i2] = ai;
    lmax = fmaxf(lmax, ai);
  }
  float sm = lmax;
  #pragma unroll
  for (int off = 1; off < 64; off <<= 1) {
    float u = __shfl_up(sm, off);
    sm = (lane >= off) ? fmaxf(sm, u) : sm;
  }
  if (lane == 63) wmax[w] = sm;
  __syncthreads();
  float pmax = -INFINITY;
  #pragma unroll
  for (int ww = 0; ww < 4; ++ww) if (ww < w) pmax = fmaxf(pmax, wmax[ww]);
  float ex = __shfl_up(sm, 1);
  float m = fmaxf(pmax, (lane == 0) ? -INFINITY : ex);
  #pragma unroll
  for (int i2 = 0; i2 < 8; ++i2) {
    m = fmaxf(m, av[i2]);
    M[h*S_LEN + base + i2] = m;
  }
}

// ---------------- Kernel 3: MFMA main, coalesced fragment loads -------------
// One Q-tile per block (big tiles first); 4 waves j-split stride 4.
__global__ __launch_bounds__(256, 2) void mlstm_main(
    const unsigned short* __restrict__ Qp, const unsigned short* __restrict__ Kp,
    const unsigned short* __restrict__ Vp,
    const float* __restrict__ cs, const float* __restrict__ a, const float* __restrict__ M,
    const float* __restrict__ out_w, float* __restrict__ out)
{
  __shared__ float red[2][QT][DHEAD];
  __shared__ float rs_red[2][QT];

  const int bb  = blockIdx.x;
  const int h   = bb & 7;          // head -> XCD locality
  const int it  = (NT-1) - (bb >> 3);  // big tiles dispatched first
  const int t   = threadIdx.x;
  const int w   = t >> 6;
  const int lane = t & 63;
  const int q32 = lane & 31;
  const int hi  = lane >> 5;

  const bf16x8* QP8 = (const bf16x8*)Qp;
  const bf16x8* KP8 = (const bf16x8*)Kp;
  const bf16x8* VP8 = (const bf16x8*)Vp;
  const float* ah = a + h*S_LEN;

  const int i0 = it*QT;
  const int iq = i0 + q32;
  const float Mi = M[h*S_LEN + iq];

  bf16x8 qf[8];
  {
    const size_t qb = ((size_t)(h*64 + it)*8)*64 + lane;
    #pragma unroll
    for (int ks = 0; ks < 8; ++ks) qf[ks] = QP8[qb + ks*64];
  }
  f32x16 acc[4];
  #pragma unroll
  for (int db = 0; db < 4; ++db)
    #pragma unroll
    for (int r = 0; r < 16; ++r) acc[db][r] = 0.f;
  float rs = 0.f;

  bf16x8 kA[8], kB[8];

  #define LOADK(BUF, JT) do {                                           \
      const size_t kb_ = ((size_t)(h*64 + (JT))*8)*64 + lane;           \
      _Pragma("unroll")                                                 \
      for (int ks_ = 0; ks_ < 8; ++ks_) BUF[ks_] = KP8[kb_ + ks_*64];   \
    } while (0)

  #define BODY(KF, JT) do {                                             \
      const int j0_ = (JT)*QT;                                          \
      const size_t vb_ = ((size_t)(h*64 + (JT))*8)*64 + lane;           \
      bf16x8 vf[4][2];                                                  \
      _Pragma("unroll")                                                 \
      for (int ksv_ = 0; ksv_ < 2; ++ksv_)                              \
        _Pragma("unroll")                                               \
        for (int db_ = 0; db_ < 4; ++db_)                               \
          vf[db_][ksv_] = VP8[vb_ + (ksv_*4 + db_)*64];                 \
      f32x16 st0, st1;                                                  \
      _Pragma("unroll")                                                 \
      for (int r_ = 0; r_ < 16; ++r_) { st0[r_] = 0.f; st1[r_] = 0.f; } \
      _Pragma("unroll")                                                 \
      for (int ks_ = 0; ks_ < 4; ++ks_) {                               \
        st0 = __builtin_amdgcn_mfma_f32_32x32x16_bf16(KF[2*ks_],   qf[2*ks_],   st0, 0, 0, 0); \
        st1 = __builtin_amdgcn_mfma_f32_32x32x16_bf16(KF[2*ks_+1], qf[2*ks_+1], st1, 0, 0, 0); \
      }                                                                 \
      const bool diag_ = ((JT) == it);                                  \
      float pw[16]; float rsl_ = 0.f;                                   \
      _Pragma("unroll")                                                 \
      for (int r_ = 0; r_ < 16; ++r_) {                                 \
        const int jl_ = (r_&3) + 8*(r_>>2) + 4*hi;                      \
        const float av_ = ah[j0_ + jl_];                                \
        float cv_ = (st0[r_] + st1[r_]) * __expf(av_ - Mi);             \
        if (diag_ && jl_ > q32) cv_ = 0.f;                              \
        pw[r_] = cv_; rsl_ += cv_;                                      \
      }                                                                 \
      rs += rsl_;                                                       \
      unsigned w00 = pk2(pw[0],pw[1]),   w02 = pk2(pw[4],pw[5]);        \
      unsigned w01 = pk2(pw[2],pw[3]),   w03 = pk2(pw[6],pw[7]);        \
      unsigned w10 = pk2(pw[8],pw[9]),   w12 = pk2(pw[12],pw[13]);      \
      unsigned w11 = pk2(pw[10],pw[11]), w13 = pk2(pw[14],pw[15]);      \
      lane32_swap(w00, w02); lane32_swap(w01, w03);                     \
      lane32_swap(w10, w12); lane32_swap(w11, w13);                     \
      u32x4 a0v; a0v[0]=w00; a0v[1]=w01; a0v[2]=w02; a0v[3]=w03;        \
      u32x4 a1v; a1v[0]=w10; a1v[1]=w11; a1v[2]=w12; a1v[3]=w13;        \
      const bf16x8 pa0 = __builtin_bit_cast(bf16x8, a0v);               \
      const bf16x8 pa1 = __builtin_bit_cast(bf16x8, a1v);               \
      _Pragma("unroll")                                                 \
      for (int db_ = 0; db_ < 4; ++db_) {                               \
        acc[db_] = __builtin_amdgcn_mfma_f32_32x32x16_bf16(pa0, vf[db_][0], acc[db_], 0, 0, 0); \
        acc[db_] = __builtin_amdgcn_mfma_f32_32x32x16_bf16(pa1, vf[db_][1], acc[db_], 0, 0, 0); \
      }                                                                 \
    } while (0)

  int jt = w;
  if (jt <= it) LOADK(kA, jt);
  while (jt <= it) {
    int nx = jt + 4;
    if (nx <= it) LOADK(kB, nx);
    BODY(kA, jt);
    jt = nx;
    if (jt > it) break;
    nx = jt + 4;
    if (nx <= it) LOADK(kA, nx);
    BODY(kB, jt);
    jt = nx;
  }
  #undef LOADK
  #undef BODY

  rs += __shfl_xor(rs, 32);

  // ---- 2-step cross-wave tree reduction in LDS ----
  if (w >= 2) {
    #pragma unroll
    for (int db = 0; db < 4; ++db)
      #pragma unroll
      for (int r = 0; r < 16; ++r) {
        const int row = (r&3) + 8*(r>>2) + 4*hi;
        red[w-2][row][db*32 + q32] = acc[db][r];
      }
    if (lane < 32) rs_red[w-2][q32] = rs;
  }
  __syncthreads();
  if (w < 2) {
    #pragma unroll
    for (int db = 0; db < 4; ++db)
      #pragma unroll
      for (int r = 0; r < 16; ++r) {
        const int row = (r&3) + 8*(r>>2) + 4*hi;
        acc[db][r] += red[w][row][db*32 + q32];
      }
    rs += rs_red[w][q32];
    #pragma unroll
    for (int db = 0; db < 4; ++db)
      #pragma unroll
      for (int r = 0; r < 16; ++r) {
        const int row = (r&3) + 8*(r>>2) + 4*hi;
        red[w][row][db*32 + q32] = acc[db][r];
      }
    if (lane < 32) rs_red[w][q32] = rs;
  }
  __syncthreads();

  // ---- epilogue: normalizer + per-head LayerNorm ----
  {
    const int r2 = t >> 3;
    const int l8 = t & 7;
    const int i  = i0 + r2;
    const float rst = rs_red[0][r2] + rs_red[1][r2];
    const float csi = cs[h*S_LEN + i];
    const float Mi2 = M[h*S_LEN + i];
    const float norm = fmaxf(fabsf(rst), __expf(-(csi + Mi2))) + 1e-6f;
    const float inv = 1.0f / norm;
    float hv[16]; float s1 = 0.f, s2 = 0.f;
    #pragma unroll
    for (int u = 0; u < 4; ++u) {
      const int d = l8*4 + u*32;
      #pragma unroll
      for (int c2 = 0; c2 < 4; ++c2) {
        float x = (red[0][r2][d+c2] + red[1][r2][d+c2]) * inv;
        hv[u*4+c2] = x; s1 += x; s2 += x*x;
      }
    }
    s1 += __shfl_xor(s1,1); s1 += __shfl_xor(s1,2); s1 += __shfl_xor(s1,4);
    s2 += __shfl_xor(s2,1); s2 += __shfl_xor(s2,2); s2 += __shfl_xor(s2,4);
    const float mean = s1*(1.f/DHEAD);
    const float var  = s2*(1.f/DHEAD) - mean*mean;
    const float rstd = rsqrtf(var + 1e-5f);
    float* op = out + (size_t)i*EDIM + h*DHEAD;
    const float* ow = out_w + h*DHEAD;
    #pragma unroll
    for (int u = 0; u < 4; ++u) {
      const int d = l8*4 + u*32;
      float4 o;
      o.x = (hv[u*4+0]-mean)*rstd*ow[d+0];
      o.y = (hv[u*4+1]-mean)*rstd*ow[d+1];
      o.z = (hv[u*4+2]-mean)*rstd*ow[d+2];
      o.w = (hv[u*4+3]-mean)*rstd*ow[d+3];
      *((float4*)(op + d)) = o;
    }
  }
}

extern "C" void kernel_launch(void* const* d_in, const int* in_sizes, int n_in,
                              void* d_out, int out_size, void* d_ws, size_t ws_size,
                              hipStream_t stream) {
  const float* q  = (const float*)d_in[0];
  const float* k  = (const float*)d_in[1];
  const float* v  = (const float*)d_in[2];
  const float* iw = (const float*)d_in[3];
  const float* ib = (const float*)d_in[4];
  const float* fw = (const float*)d_in[5];
  const float* fb = (const float*)d_in[6];
  const float* ow = (const float*)d_in[7];
  float* out = (float*)d_out;
  float* ws = (float*)d_ws;
  float* ig = ws;
  float* fg = ws + 1*NHEAD*S_LEN;
  float* cs = ws + 2*NHEAD*S_LEN;
  float* aa = ws + 3*NHEAD*S_LEN;
  float* Mm = ws + 4*NHEAD*S_LEN;
  unsigned short* Qp = (unsigned short*)(ws + 5*NHEAD*S_LEN);
  unsigned short* Kp = Qp + (size_t)S_LEN*EDIM;
  unsigned short* Vp = Kp + (size_t)S_LEN*EDIM;

  hipLaunchKernelGGL(gates_pack_kernel, dim3(S_LEN/8), dim3(256), 0, stream,
                     q, k, v, iw, ib, fw, fb, ig, fg, Qp, Kp, Vp);
  hipLaunchKernelGGL(scan_kernel, dim3(NHEAD), dim3(256), 0, stream,
                     ig, fg, cs, aa, Mm);
  hipLaunchKernelGGL(mlstm_main, dim3(NHEAD*NT), dim3(256), 0, stream,
                     Qp, Kp, Vp, cs, aa, Mm, ow, out);
}

// Round 6
// 50.422 us; speedup vs baseline: 9.5571x; 1.1328x over previous
//
#include <hip/hip_runtime.h>
#include <hip/hip_bf16.h>
#include <math.h>

#define S_LEN 2048
#define EDIM  1024
#define NHEAD 8
#define DHEAD 128
#define QT    32
#define NT    64            // S_LEN/QT
#define SCL   0.08838834764831845f   // 1/sqrt(128)

typedef __bf16 bf16x8 __attribute__((ext_vector_type(8)));
typedef __bf16 bf16x2 __attribute__((ext_vector_type(2)));
typedef float  f32x16 __attribute__((ext_vector_type(16)));
typedef unsigned int u32x4 __attribute__((ext_vector_type(4)));

__device__ __forceinline__ unsigned pk2(float a, float b) {
  bf16x2 t; t[0] = (__bf16)a; t[1] = (__bf16)b;
  return __builtin_bit_cast(unsigned, t);
}
__device__ __forceinline__ unsigned short bfb(float x) {
  return __builtin_bit_cast(unsigned short, (__bf16)x);
}
__device__ __forceinline__ void lane32_swap(unsigned &x, unsigned &y) {
  asm volatile("v_permlane32_swap_b32 %0, %1" : "+v"(x), "+v"(y));
}

// ---------------- Kernel 1: gates + fragment-order bf16 pack ----------------
// Block = 8 s-rows (one V e-octet). Packs Qp/Kp/Vp so main-kernel fragment
// loads are single coalesced 1KB dwordx4 per (wave, ks).
//   Qp/Kp entry(h,tile,ks,l)      : row tile*32+(l&31), elems h*128+(l>>5)*8+ks*16+e
//   Vp entry(h,tile,ksv,db,l)     : col h*128+db*32+(l&31), rows tile*32+(l>>5)*8+ksv*16+e
__global__ __launch_bounds__(256) void gates_pack_kernel(
    const float* __restrict__ q, const float* __restrict__ k, const float* __restrict__ v,
    const float* __restrict__ iw, const float* __restrict__ ib,
    const float* __restrict__ fw, const float* __restrict__ fb,
    float* __restrict__ ig, float* __restrict__ fg,
    unsigned short* __restrict__ Qp, unsigned short* __restrict__ Kp,
    unsigned short* __restrict__ Vp)
{
  __shared__ float gl[8][3072];
  const int s0 = blockIdx.x * 8;
  const int t = threadIdx.x;
  const int w = t >> 6, lane = t & 63;
  // phase A: stage 8 rows of concat(q,k,v)
  #pragma unroll
  for (int rr = 0; rr < 8; ++rr) {
    const float4* qs = (const float4*)(q + (size_t)(s0+rr)*EDIM);
    const float4* ks = (const float4*)(k + (size_t)(s0+rr)*EDIM);
    const float4* vs = (const float4*)(v + (size_t)(s0+rr)*EDIM);
    float4* dst = (float4*)&gl[rr][0];
    dst[t]       = qs[t];
    dst[t + 256] = ks[t];
    dst[t + 512] = vs[t];
  }
  __syncthreads();
  // phase B: dots. wave w -> outputs c in {w, w+4, w+8, w+12}, 8 rows each.
  float sum[4][8];
  #pragma unroll
  for (int ci = 0; ci < 4; ++ci)
    #pragma unroll
    for (int rr = 0; rr < 8; ++rr) sum[ci][rr] = 0.f;
  for (int ch = 0; ch < 12; ++ch) {
    float4 wv[4];
    #pragma unroll
    for (int ci = 0; ci < 4; ++ci) {
      const int c = w + 4*ci;
      const float* wr = (c >= 8 ? fw : iw) + (size_t)(c & 7)*3*EDIM;
      wv[ci] = ((const float4*)wr)[ch*64 + lane];
    }
    #pragma unroll
    for (int rr = 0; rr < 8; ++rr) {
      const float4 g = ((const float4*)&gl[rr][0])[ch*64 + lane];
      #pragma unroll
      for (int ci = 0; ci < 4; ++ci)
        sum[ci][rr] += g.x*wv[ci].x + g.y*wv[ci].y + g.z*wv[ci].z + g.w*wv[ci].w;
    }
  }
  #pragma unroll
  for (int ci = 0; ci < 4; ++ci)
    #pragma unroll
    for (int rr = 0; rr < 8; ++rr) {
      float s = sum[ci][rr];
      #pragma unroll
      for (int off = 32; off; off >>= 1) s += __shfl_xor(s, off);
      if (lane == 0) {
        const int c = w + 4*ci;
        const int hh = c & 7;
        if (c >= 8) fg[hh*S_LEN + s0 + rr] = s + fb[hh];
        else        ig[hh*S_LEN + s0 + rr] = s + ib[hh];
      }
    }
  // phase C: pack Q (xSCL) and K. thread t owns elems 4t..4t+3 of each row.
  {
    const int hh = t >> 5;
    const int ks = (t >> 2) & 7;
    const int hi = (t >> 1) & 1;
    const int half = (t & 1);           // 8B half within 16B entry
    const int jt = s0 >> 5;
    #pragma unroll
    for (int rr = 0; rr < 8; ++rr) {
      const int l31 = (s0 & 31) + rr;
      const size_t idx16 = ((size_t)(hh*64 + jt)*8 + ks)*64 + hi*32 + l31;
      const float4 qv = ((const float4*)&gl[rr][0])[t];
      const float4 kv = ((const float4*)&gl[rr][0])[t + 256];
      ushort4 qo, ko;
      qo.x = bfb(qv.x*SCL); qo.y = bfb(qv.y*SCL); qo.z = bfb(qv.z*SCL); qo.w = bfb(qv.w*SCL);
      ko.x = bfb(kv.x); ko.y = bfb(kv.y); ko.z = bfb(kv.z); ko.w = bfb(kv.w);
      *(ushort4*)(Qp + idx16*8 + half*4) = qo;
      *(ushort4*)(Kp + idx16*8 + half*4) = ko;
    }
  }
  // phase D: pack V (transposed). Block covers one e-octet (8 rows).
  {
    const int hh  = t >> 5;
    const int c31 = t & 31;
    const int jt  = s0 >> 5;
    const int o   = (s0 & 31) >> 3;     // octet index within tile
    const int hiv = o & 1, ksv = o >> 1;
    #pragma unroll
    for (int db = 0; db < 4; ++db) {
      const int col = hh*128 + db*32 + c31;
      bf16x8 e;
      #pragma unroll
      for (int rr = 0; rr < 8; ++rr) e[rr] = (__bf16)gl[rr][2048 + col];
      const size_t idx16 = (((size_t)(hh*64 + jt)*2 + ksv)*4 + db)*64 + hiv*32 + c31;
      *(bf16x8*)(Vp + idx16*8) = e;
    }
  }
}

// ---------------- Kernel 2: per-head scans (shfl-based, 2 barriers) ---------
__global__ __launch_bounds__(256) void scan_kernel(
    const float* __restrict__ ig, const float* __restrict__ fg,
    float* __restrict__ cs, float* __restrict__ a, float* __restrict__ M)
{
  __shared__ float wsum[4];
  __shared__ float wmax[4];
  const int h = blockIdx.x, t = threadIdx.x;
  const int w = t >> 6, lane = t & 63;
  const int base = t*8;
  const float* fgh = fg + h*S_LEN;
  const float* igh = ig + h*S_LEN;
  float lv[8];
  float loc = 0.f;
  #pragma unroll
  for (int i2 = 0; i2 < 8; ++i2) {
    float x = fgh[base + i2];
    float ls = fminf(x, 0.f) - log1pf(expf(-fabsf(x)));
    lv[i2] = ls; loc += ls;
  }
  float sc = loc;
  #pragma unroll
  for (int off = 1; off < 64; off <<= 1) {
    float u = __shfl_up(sc, off);
    sc += (lane >= off) ? u : 0.f;
  }
  if (lane == 63) wsum[w] = sc;
  __syncthreads();
  float prefix = 0.f;
  #pragma unroll
  for (int ww = 0; ww < 4; ++ww) if (ww < w) prefix += wsum[ww];
  float c = prefix + sc - loc;  // exclusive prefix for this thread
  float av[8]; float lmax = -INFINITY;
  #pragma unroll
  for (int i2 = 0; i2 < 8; ++i2) {
    c += lv[i2];
    cs[h*S_LEN + base + i2] = c;
    float ai = igh[base + i2] - c;
    av[i2] = ai;
    a[h*S_LEN + base + i2] = ai;
    lmax = fmaxf(lmax, ai);
  }
  float sm = lmax;
  #pragma unroll
  for (int off = 1; off < 64; off <<= 1) {
    float u = __shfl_up(sm, off);
    sm = (lane >= off) ? fmaxf(sm, u) : sm;
  }
  if (lane == 63) wmax[w] = sm;
  __syncthreads();
  float pmax = -INFINITY;
  #pragma unroll
  for (int ww = 0; ww < 4; ++ww) if (ww < w) pmax = fmaxf(pmax, wmax[ww]);
  float ex = __shfl_up(sm, 1);
  float m = fmaxf(pmax, (lane == 0) ? -INFINITY : ex);
  #pragma unroll
  for (int i2 = 0; i2 < 8; ++i2) {
    m = fmaxf(m, av[i2]);
    M[h*S_LEN + base + i2] = m;
  }
}

// ---------------- Kernel 3: MFMA main, coalesced fragment loads -------------
// Balanced pairing: co-resident blocks (b, b+256) carry tiles (63-m, m) ->
// constant 65 j-tiles per CU. a[] loads hoisted to BODY top (latency hidden
// under the QK MFMA chain); direct loads, no cross-lane ops (R5 post-mortem).
__global__ __launch_bounds__(256, 2) void mlstm_main(
    const unsigned short* __restrict__ Qp, const unsigned short* __restrict__ Kp,
    const unsigned short* __restrict__ Vp,
    const float* __restrict__ cs, const float* __restrict__ a, const float* __restrict__ M,
    const float* __restrict__ out_w, float* __restrict__ out)
{
  __shared__ float red[2][QT][DHEAD];
  __shared__ float rs_red[2][QT];

  const int bb  = blockIdx.x;
  const int h   = bb & 7;          // head -> XCD locality
  const int l   = bb >> 3;         // 0..63
  const int it  = (l < 32) ? (63 - l) : (l - 32);   // balanced big/small pairing
  const int t   = threadIdx.x;
  const int w   = t >> 6;
  const int lane = t & 63;
  const int q32 = lane & 31;
  const int hi  = lane >> 5;

  const bf16x8* QP8 = (const bf16x8*)Qp;
  const bf16x8* KP8 = (const bf16x8*)Kp;
  const bf16x8* VP8 = (const bf16x8*)Vp;
  const float* ah = a + h*S_LEN;

  const int i0 = it*QT;
  const int iq = i0 + q32;
  const float Mi = M[h*S_LEN + iq];

  bf16x8 qf[8];
  {
    const size_t qb = ((size_t)(h*64 + it)*8)*64 + lane;
    #pragma unroll
    for (int ks = 0; ks < 8; ++ks) qf[ks] = QP8[qb + ks*64];
  }
  f32x16 acc[4];
  #pragma unroll
  for (int db = 0; db < 4; ++db)
    #pragma unroll
    for (int r = 0; r < 16; ++r) acc[db][r] = 0.f;
  float rs = 0.f;

  bf16x8 kA[8], kB[8];

  #define LOADK(BUF, JT) do {                                           \
      const size_t kb_ = ((size_t)(h*64 + (JT))*8)*64 + lane;           \
      _Pragma("unroll")                                                 \
      for (int ks_ = 0; ks_ < 8; ++ks_) BUF[ks_] = KP8[kb_ + ks_*64];   \
    } while (0)

  #define BODY(KF, JT) do {                                             \
      const int j0_ = (JT)*QT;                                          \
      float av_[16];                                                    \
      _Pragma("unroll")                                                 \
      for (int r_ = 0; r_ < 16; ++r_)                                   \
        av_[r_] = ah[j0_ + ((r_&3) + 8*(r_>>2) + 4*hi)];                \
      const size_t vb_ = ((size_t)(h*64 + (JT))*8)*64 + lane;           \
      bf16x8 vf[4][2];                                                  \
      _Pragma("unroll")                                                 \
      for (int ksv_ = 0; ksv_ < 2; ++ksv_)                              \
        _Pragma("unroll")                                               \
        for (int db_ = 0; db_ < 4; ++db_)                               \
          vf[db_][ksv_] = VP8[vb_ + (ksv_*4 + db_)*64];                 \
      f32x16 st0, st1;                                                  \
      _Pragma("unroll")                                                 \
      for (int r_ = 0; r_ < 16; ++r_) { st0[r_] = 0.f; st1[r_] = 0.f; } \
      _Pragma("unroll")                                                 \
      for (int ks_ = 0; ks_ < 4; ++ks_) {                               \
        st0 = __builtin_amdgcn_mfma_f32_32x32x16_bf16(KF[2*ks_],   qf[2*ks_],   st0, 0, 0, 0); \
        st1 = __builtin_amdgcn_mfma_f32_32x32x16_bf16(KF[2*ks_+1], qf[2*ks_+1], st1, 0, 0, 0); \
      }                                                                 \
      const bool diag_ = ((JT) == it);                                  \
      float pw[16]; float rsl_ = 0.f;                                   \
      _Pragma("unroll")                                                 \
      for (int r_ = 0; r_ < 16; ++r_) {                                 \
        const int jl_ = (r_&3) + 8*(r_>>2) + 4*hi;                      \
        float cv_ = (st0[r_] + st1[r_]) * __expf(av_[r_] - Mi);         \
        if (diag_ && jl_ > q32) cv_ = 0.f;                              \
        pw[r_] = cv_; rsl_ += cv_;                                      \
      }                                                                 \
      rs += rsl_;                                                       \
      unsigned w00 = pk2(pw[0],pw[1]),   w02 = pk2(pw[4],pw[5]);        \
      unsigned w01 = pk2(pw[2],pw[3]),   w03 = pk2(pw[6],pw[7]);        \
      unsigned w10 = pk2(pw[8],pw[9]),   w12 = pk2(pw[12],pw[13]);      \
      unsigned w11 = pk2(pw[10],pw[11]), w13 = pk2(pw[14],pw[15]);      \
      lane32_swap(w00, w02); lane32_swap(w01, w03);                     \
      lane32_swap(w10, w12); lane32_swap(w11, w13);                     \
      u32x4 a0v; a0v[0]=w00; a0v[1]=w01; a0v[2]=w02; a0v[3]=w03;        \
      u32x4 a1v; a1v[0]=w10; a1v[1]=w11; a1v[2]=w12; a1v[3]=w13;        \
      const bf16x8 pa0 = __builtin_bit_cast(bf16x8, a0v);               \
      const bf16x8 pa1 = __builtin_bit_cast(bf16x8, a1v);               \
      _Pragma("unroll")                                                 \
      for (int db_ = 0; db_ < 4; ++db_) {                               \
        acc[db_] = __builtin_amdgcn_mfma_f32_32x32x16_bf16(pa0, vf[db_][0], acc[db_], 0, 0, 0); \
        acc[db_] = __builtin_amdgcn_mfma_f32_32x32x16_bf16(pa1, vf[db_][1], acc[db_], 0, 0, 0); \
      }                                                                 \
    } while (0)

  int jt = w;
  if (jt <= it) LOADK(kA, jt);
  while (jt <= it) {
    int nx = jt + 4;
    if (nx <= it) LOADK(kB, nx);
    BODY(kA, jt);
    jt = nx;
    if (jt > it) break;
    nx = jt + 4;
    if (nx <= it) LOADK(kA, nx);
    BODY(kB, jt);
    jt = nx;
  }
  #undef LOADK
  #undef BODY

  rs += __shfl_xor(rs, 32);

  // ---- 2-step cross-wave tree reduction in LDS ----
  if (w >= 2) {
    #pragma unroll
    for (int db = 0; db < 4; ++db)
      #pragma unroll
      for (int r = 0; r < 16; ++r) {
        const int row = (r&3) + 8*(r>>2) + 4*hi;
        red[w-2][row][db*32 + q32] = acc[db][r];
      }
    if (lane < 32) rs_red[w-2][q32] = rs;
  }
  __syncthreads();
  if (w < 2) {
    #pragma unroll
    for (int db = 0; db < 4; ++db)
      #pragma unroll
      for (int r = 0; r < 16; ++r) {
        const int row = (r&3) + 8*(r>>2) + 4*hi;
        acc[db][r] += red[w][row][db*32 + q32];
      }
    rs += rs_red[w][q32];
    #pragma unroll
    for (int db = 0; db < 4; ++db)
      #pragma unroll
      for (int r = 0; r < 16; ++r) {
        const int row = (r&3) + 8*(r>>2) + 4*hi;
        red[w][row][db*32 + q32] = acc[db][r];
      }
    if (lane < 32) rs_red[w][q32] = rs;
  }
  __syncthreads();

  // ---- epilogue: normalizer + per-head LayerNorm ----
  {
    const int r2 = t >> 3;
    const int l8 = t & 7;
    const int i  = i0 + r2;
    const float rst = rs_red[0][r2] + rs_red[1][r2];
    const float csi = cs[h*S_LEN + i];
    const float Mi2 = M[h*S_LEN + i];
    const float norm = fmaxf(fabsf(rst), __expf(-(csi + Mi2))) + 1e-6f;
    const float inv = 1.0f / norm;
    float hv[16]; float s1 = 0.f, s2 = 0.f;
    #pragma unroll
    for (int u = 0; u < 4; ++u) {
      const int d = l8*4 + u*32;
      #pragma unroll
      for (int c2 = 0; c2 < 4; ++c2) {
        float x = (red[0][r2][d+c2] + red[1][r2][d+c2]) * inv;
        hv[u*4+c2] = x; s1 += x; s2 += x*x;
      }
    }
    s1 += __shfl_xor(s1,1); s1 += __shfl_xor(s1,2); s1 += __shfl_xor(s1,4);
    s2 += __shfl_xor(s2,1); s2 += __shfl_xor(s2,2); s2 += __shfl_xor(s2,4);
    const float mean = s1*(1.f/DHEAD);
    const float var  = s2*(1.f/DHEAD) - mean*mean;
    const float rstd = rsqrtf(var + 1e-5f);
    float* op = out + (size_t)i*EDIM + h*DHEAD;
    const float* ow = out_w + h*DHEAD;
    #pragma unroll
    for (int u = 0; u < 4; ++u) {
      const int d = l8*4 + u*32;
      float4 o;
      o.x = (hv[u*4+0]-mean)*rstd*ow[d+0];
      o.y = (hv[u*4+1]-mean)*rstd*ow[d+1];
      o.z = (hv[u*4+2]-mean)*rstd*ow[d+2];
      o.w = (hv[u*4+3]-mean)*rstd*ow[d+3];
      *((float4*)(op + d)) = o;
    }
  }
}

extern "C" void kernel_launch(void* const* d_in, const int* in_sizes, int n_in,
                              void* d_out, int out_size, void* d_ws, size_t ws_size,
                              hipStream_t stream) {
  const float* q  = (const float*)d_in[0];
  const float* k  = (const float*)d_in[1];
  const float* v  = (const float*)d_in[2];
  const float* iw = (const float*)d_in[3];
  const float* ib = (const float*)d_in[4];
  const float* fw = (const float*)d_in[5];
  const float* fb = (const float*)d_in[6];
  const float* ow = (const float*)d_in[7];
  float* out = (float*)d_out;
  float* ws = (float*)d_ws;
  float* ig = ws;
  float* fg = ws + 1*NHEAD*S_LEN;
  float* cs = ws + 2*NHEAD*S_LEN;
  float* aa = ws + 3*NHEAD*S_LEN;
  float* Mm = ws + 4*NHEAD*S_LEN;
  unsigned short* Qp = (unsigned short*)(ws + 5*NHEAD*S_LEN);
  unsigned short* Kp = Qp + (size_t)S_LEN*EDIM;
  unsigned short* Vp = Kp + (size_t)S_LEN*EDIM;

  hipLaunchKernelGGL(gates_pack_kernel, dim3(S_LEN/8), dim3(256), 0, stream,
                     q, k, v, iw, ib, fw, fb, ig, fg, Qp, Kp, Vp);
  hipLaunchKernelGGL(scan_kernel, dim3(NHEAD), dim3(256), 0, stream,
                     ig, fg, cs, aa, Mm);
  hipLaunchKernelGGL(mlstm_main, dim3(NHEAD*NT), dim3(256), 0, stream,
                     Qp, Kp, Vp, cs, aa, Mm, ow, out);
}